// Round 13
// baseline (1197.578 us; speedup 1.0000x reference)
//
#include <hip/hip_runtime.h>
#include <math.h>

#define B_   32
#define L_   512
#define E_   300
#define H_   256
#define T_   4
#define NTOK 16384  // B*L
#define XGLD 2048   // 2 directions * 4H
#define SENT 2.0f   // impossible h value: |h| = |sigm*tanh| < 1

typedef float f32x4 __attribute__((ext_vector_type(4)));
typedef float f32x2 __attribute__((ext_vector_type(2)));

__device__ __forceinline__ float fsigmoid_(float x) { return 1.0f / (1.0f + __expf(-x)); }
__device__ __forceinline__ float ftanh_(float x) {
  return 1.0f - 2.0f / (__expf(2.0f * x) + 1.0f);   // exact limits at +-inf
}

// LLC-coherent (agent-scope) vector ops: sc0 sc1 bypass L1/L2 like relaxed
// agent atomics, but vectorized. Caller must s_waitcnt vmcnt before using loads.
__device__ __forceinline__ void llc_store_f32(float* p, float v) {
  asm volatile("global_store_dword %0, %1, off sc0 sc1" :: "v"(p), "v"(v) : "memory");
}
__device__ __forceinline__ void llc_store_f32x4(float* p, f32x4 v) {
  asm volatile("global_store_dwordx4 %0, %1, off sc0 sc1" :: "v"(p), "v"(v) : "memory");
}
__device__ __forceinline__ f32x4 llc_load_f32x4(const float* p) {
  f32x4 r;
  asm volatile("global_load_dwordx4 %0, %1, off sc0 sc1" : "=&v"(r) : "v"(p) : "memory");
  return r;
}

// ---------- stage A: xg[row][d*1024+g] = emb[wid[row]] . Wih_d[g] + b_d[g] ----------
#define BM 64
#define BN 64
#define BK 20
__global__ __launch_bounds__(256) void xproj_kernel(
    const int*   __restrict__ wid,    // [NTOK]
    const float* __restrict__ emb,    // [V][300]
    const float* __restrict__ wih_f,  // [1024][300]
    const float* __restrict__ wih_b,
    const float* __restrict__ b_f,
    const float* __restrict__ b_b,
    float* __restrict__ xg)           // [NTOK][2048]
{
  __shared__ float Ast[BK][BM];      // [k][m]
  __shared__ float Bst[BK][BN];      // [k][n]
  __shared__ int   wid_s[BM];

  const int tid = threadIdx.x;
  const int m0 = blockIdx.y * BM;
  const int n0 = blockIdx.x * BN;    // global col 0..2047
  const int d  = n0 >> 10;
  const float* wih  = d ? wih_b : wih_f;
  const float* bias = d ? b_b  : b_f;
  const int g0 = n0 & 1023;

  if (tid < BM) wid_s[tid] = wid[m0 + tid];
  __syncthreads();

  const int row = tid & 63;          // staging row
  const int qa  = tid >> 6;          // staging quad 0..3 (5th quad by qa==0)
  const int tx = tid & 15, ty = tid >> 4;

  float acc[4][4] = {};

  for (int k0 = 0; k0 < 300; k0 += BK) {
    {
      const float* erow = emb + (size_t)wid_s[row] * E_ + k0;
      f32x4 va = *(const f32x4*)(erow + qa * 4);
#pragma unroll
      for (int e = 0; e < 4; ++e) Ast[qa * 4 + e][row] = va[e];
      if (qa == 0) {
        f32x4 vb = *(const f32x4*)(erow + 16);
#pragma unroll
        for (int e = 0; e < 4; ++e) Ast[16 + e][row] = vb[e];
      }
    }
    {
      const float* wrow = wih + (size_t)(g0 + row) * E_ + k0;
      f32x4 va = *(const f32x4*)(wrow + qa * 4);
#pragma unroll
      for (int e = 0; e < 4; ++e) Bst[qa * 4 + e][row] = va[e];
      if (qa == 0) {
        f32x4 vb = *(const f32x4*)(wrow + 16);
#pragma unroll
        for (int e = 0; e < 4; ++e) Bst[16 + e][row] = vb[e];
      }
    }
    __syncthreads();

#pragma unroll
    for (int k = 0; k < BK; ++k) {
      f32x4 a4 = *(const f32x4*)&Ast[k][ty * 4];
      f32x4 b4 = *(const f32x4*)&Bst[k][tx * 4];
      acc[0][0] += a4.x * b4.x; acc[0][1] += a4.x * b4.y;
      acc[0][2] += a4.x * b4.z; acc[0][3] += a4.x * b4.w;
      acc[1][0] += a4.y * b4.x; acc[1][1] += a4.y * b4.y;
      acc[1][2] += a4.y * b4.z; acc[1][3] += a4.y * b4.w;
      acc[2][0] += a4.z * b4.x; acc[2][1] += a4.z * b4.y;
      acc[2][2] += a4.z * b4.z; acc[2][3] += a4.z * b4.w;
      acc[3][0] += a4.w * b4.x; acc[3][1] += a4.w * b4.y;
      acc[3][2] += a4.w * b4.z; acc[3][3] += a4.w * b4.w;
    }
    __syncthreads();
  }

#pragma unroll
  for (int i = 0; i < 4; ++i) {
    const int r = m0 + ty * 4 + i;
    float* op = xg + (size_t)r * XGLD + n0 + tx * 4;
#pragma unroll
    for (int jj = 0; jj < 4; ++jj)
      op[jj] = acc[i][jj] + bias[g0 + tx * 4 + jj];
  }
}

// ---------- sentinel fill for h_all (replay-safe, runs every launch) ----------
__global__ __launch_bounds__(256) void fill_sentinel(float* p, int n4) {
  int i = blockIdx.x * 256 + threadIdx.x;
  if (i < n4) {
    f32x4 v = {SENT, SENT, SENT, SENT};
    llc_store_f32x4(p + (size_t)i * 4, v);
  }
}

// ---------- stage B: LSTM, 256 blocks, 2-phase pipeline, unit-tile GEMM (kp=16) ------
// Block = (d, q eighth of 4 batches, sl slice of 16 units, unit-major rows).
// Phases: A = batches {0,1}, B = {2,3}. 4-slot schedule per step:
//   slot1 GEMM_A(s) | slot2 reduce_A(s)+pub || spin_B(s-1) | slot3 GEMM_B(s) |
//   slot4 reduce_B(s)+pub || spin_A(s)
// GEMM mapping: tid = kp*32 + bl_loc*16 + rp. Thread computes the 4 gates of
// unit rp for one batch over k-chunk [16kp,16kp+16): 4 ds_read_b128 + 64 FMA.
// Partial = f32x4 of gates -> reduce layout unchanged (sums 16 kp).
__global__ __launch_bounds__(512, 2) void lstm_kernel(
    const float* __restrict__ xg,     // [NTOK][2048]
    const float* __restrict__ whh_f,  // [1024][256]
    const float* __restrict__ whh_b,  // [1024][256]
    float*       h_all)               // [16 grp][512 t][4 bl][256 j]
{
  const int bid = blockIdx.x;        // 0..255
  const int d   = bid >> 7;
  const int q   = (bid >> 4) & 7;    // batch eighth
  const int sl  = bid & 15;          // slice
  const int tid = threadIdx.x;
  const int kp  = tid >> 5;          // 0..15 (k-chunk of 16)
  const int bl_loc = (tid >> 4) & 1; // batch within phase
  const int rp  = tid & 15;          // unit within slice
  const float* __restrict__ whh = d ? whh_b : whh_f;

  __shared__ float h_lds[4 * 260];            // h[bl][k+pad]              (4.2 KB)
  __shared__ float part_lds[2 * 16 * 2 * 72]; // [ph][kp][bl_loc][row+pad] (18.4 KB)

  // ---- per-thread weights: 4 gates of unit rp, k-chunk kp (16 k = 4 f32x4) ----
  f32x4 wreg[4][4];
#pragma unroll
  for (int r = 0; r < 4; ++r) {
    const int grow = r * 256 + sl * 16 + rp;
    const float* rpw = whh + (size_t)grow * H_ + kp * 16;
#pragma unroll
    for (int qq = 0; qq < 4; ++qq) wreg[r][qq] = *(const f32x4*)(rpw + qq * 4);
  }

  for (int idx = tid; idx < 4 * 260; idx += 512) h_lds[idx] = 0.f;
  __syncthreads();

  float* hgrp = h_all + (size_t)(d * 8 + q) * (L_ * 1024);   // [512 t][4 bl][256 j]

  // reduce-thread state: tid<32 -> phase A (bl 0,1); tid 32..63 -> phase B (bl 2,3)
  const int r_u  = (tid & 31) >> 1;
  const int r_bl = (tid < 32) ? (tid & 1) : (2 + (tid & 1));
  float c = 0.f;
  const float* xbase = xg + ((size_t)(q * 4 + r_bl) * L_) * XGLD + d * 1024 + sl * 16 + r_u;
  float x0 = 0.f, x1 = 0.f, x2 = 0.f, x3 = 0.f;
  if (tid < 64) {
    const int t0 = d ? (L_ - 1) : 0;
    const float* xp = xbase + (size_t)t0 * XGLD;
    x0 = xp[0]; x1 = xp[256]; x2 = xp[512]; x3 = xp[768];
  }

#define GEMM_PHASE(PH, BLBASE)                                                \
  do {                                                                        \
    const int blg = (BLBASE) + bl_loc;                                        \
    const float* hb = &h_lds[blg * 260 + kp * 16];                            \
    float a0 = 0.f, a1 = 0.f, a2 = 0.f, a3 = 0.f;                             \
    _Pragma("unroll")                                                         \
    for (int i = 0; i < 4; ++i) {                                             \
      f32x4 hv = *(const f32x4*)(hb + i * 4);                                 \
      a0 += wreg[0][i].x * hv.x + wreg[0][i].y * hv.y                         \
          + wreg[0][i].z * hv.z + wreg[0][i].w * hv.w;                        \
      a1 += wreg[1][i].x * hv.x + wreg[1][i].y * hv.y                         \
          + wreg[1][i].z * hv.z + wreg[1][i].w * hv.w;                        \
      a2 += wreg[2][i].x * hv.x + wreg[2][i].y * hv.y                         \
          + wreg[2][i].z * hv.z + wreg[2][i].w * hv.w;                        \
      a3 += wreg[3][i].x * hv.x + wreg[3][i].y * hv.y                         \
          + wreg[3][i].z * hv.z + wreg[3][i].w * hv.w;                        \
    }                                                                         \
    f32x4 pv = {a0, a1, a2, a3};                                              \
    *(f32x4*)&part_lds[(PH) * 2304 + kp * 144 + bl_loc * 72 + rp * 4] = pv;   \
  } while (0)

#define REDUCE_PUBLISH(PH, TT, TN)                                            \
  do {                                                                        \
    f32x4 g = {x0, x1, x2, x3};                                               \
    _Pragma("unroll")                                                         \
    for (int k2 = 0; k2 < 16; ++k2)                                           \
      g += *(const f32x4*)&part_lds[(PH) * 2304 + k2 * 144                    \
                                    + (tid & 1) * 72 + r_u * 4];              \
    float gi = fsigmoid_(g.x);                                                \
    float gf = fsigmoid_(g.y);                                                \
    float gg = ftanh_(g.z);                                                   \
    float go = fsigmoid_(g.w);                                                \
    c = gf * c + gi * gg;                                                     \
    float h = go * ftanh_(c);                                                 \
    llc_store_f32(&hgrp[(size_t)(TT) * 1024 + r_bl * 256 + sl * 16 + r_u], h);\
    if ((TN) >= 0) {                                                          \
      const float* xp = xbase + (size_t)(TN) * XGLD;                          \
      x0 = xp[0]; x1 = xp[256]; x2 = xp[512]; x3 = xp[768];                   \
    }                                                                         \
  } while (0)

#define SPIN_LOAD(BLBASE, TT)                                                 \
  do {                                                                        \
    const int i = tid - 64;                                                   \
    const int blg = (BLBASE) + (i >> 6);                                      \
    const int j4 = (i & 63) * 4;                                              \
    const float* p0 = hgrp + (size_t)(TT) * 1024 + blg * 256 + j4;            \
    f32x4 v0;                                                                 \
    bool bad;                                                                 \
    do {                                                                      \
      v0 = llc_load_f32x4(p0);                                                \
      asm volatile("s_waitcnt vmcnt(0)" ::: "memory");                        \
      __builtin_amdgcn_sched_barrier(0);                                      \
      bad = (v0.x == SENT) | (v0.y == SENT) | (v0.z == SENT) | (v0.w == SENT);\
    } while (bad);                                                            \
    *(f32x4*)&h_lds[blg * 260 + j4] = v0;                                     \
  } while (0)

  for (int s = 0; s < L_; ++s) {
    const int t  = d ? (L_ - 1 - s) : s;
    const int tp = d ? (t + 1) : (t - 1);          // previous step's time index
    const int tn = (s < L_ - 1) ? (d ? (t - 1) : (t + 1)) : -1;

    // ---- slot1: GEMM phase A ----
    GEMM_PHASE(0, 0);
    __syncthreads();

    // ---- slot2: reduce/publish A(s)  ||  spin B(s-1) ----
    if (tid < 32) {
      REDUCE_PUBLISH(0, t, tn);
    } else if (s > 0 && tid >= 64 && tid < 192) {
      SPIN_LOAD(2, tp);
    }
    __syncthreads();

    // ---- slot3: GEMM phase B ----
    GEMM_PHASE(1, 2);
    __syncthreads();

    // ---- slot4: reduce/publish B(s)  ||  spin A(s) ----
    if (tid >= 32 && tid < 64) {
      REDUCE_PUBLISH(1, t, tn);
    } else if (s < L_ - 1 && tid >= 64 && tid < 192) {
      SPIN_LOAD(0, t);
    }
    __syncthreads();
  }

#undef GEMM_PHASE
#undef REDUCE_PUBLISH
#undef SPIN_LOAD
}

// ---------- emissions: block = (t, q); em[b][t][tag] = bout + h_f.Wf + h_b.Wb ------
__global__ __launch_bounds__(256) void emis_kernel(
    const float* __restrict__ h_all,  // [16][512][4][256]
    const float* __restrict__ wout,   // [4][512]
    const float* __restrict__ bout,   // [4]
    float* __restrict__ em)           // [32][512][4]
{
  __shared__ float hf_l[1024];   // [bl][j]
  __shared__ float hb_l[1024];
  __shared__ float wsl[2048];

  const int t  = blockIdx.x >> 3;
  const int q  = blockIdx.x & 7;
  const int tid = threadIdx.x;
  const float* hfp = h_all + ((size_t)(0 + q) * L_ + t) * 1024;
  const float* hbp = h_all + ((size_t)(8 + q) * L_ + t) * 1024;

  if (tid < 256) {
    *(f32x4*)&hf_l[tid * 4] = *(const f32x4*)&hfp[tid * 4];
    *(f32x4*)&hb_l[tid * 4] = *(const f32x4*)&hbp[tid * 4];
  }
  for (int i = tid; i < 2048; i += 256) wsl[i] = wout[i];
  __syncthreads();

  const int bl = tid >> 6, lane = tid & 63;
  float s0 = 0.f, s1 = 0.f, s2 = 0.f, s3 = 0.f;
#pragma unroll
  for (int i = 0; i < 4; ++i) {
    const int j = i * 64 + lane;
    const float hfv = hf_l[bl * 256 + j], hbv = hb_l[bl * 256 + j];
    s0 += hfv * wsl[0 * 512 + j] + hbv * wsl[0 * 512 + 256 + j];
    s1 += hfv * wsl[1 * 512 + j] + hbv * wsl[1 * 512 + 256 + j];
    s2 += hfv * wsl[2 * 512 + j] + hbv * wsl[2 * 512 + 256 + j];
    s3 += hfv * wsl[3 * 512 + j] + hbv * wsl[3 * 512 + 256 + j];
  }
#pragma unroll
  for (int m = 1; m < 64; m <<= 1) {
    s0 += __shfl_xor(s0, m, 64);
    s1 += __shfl_xor(s1, m, 64);
    s2 += __shfl_xor(s2, m, 64);
    s3 += __shfl_xor(s3, m, 64);
  }
  if (lane == 0) {
    float* ep = em + ((size_t)(q * 4 + bl) * L_ + t) * 4;
    ep[0] = s0 + bout[0]; ep[1] = s1 + bout[1];
    ep[2] = s2 + bout[2]; ep[3] = s3 + bout[3];
  }
}

// ---------- Viterbi decode: one block per batch, em/hist staged in LDS ----------
__global__ __launch_bounds__(64) void viterbi_kernel(
    const float* __restrict__ em,      // [32][512][4]  (bias included)
    const float* __restrict__ trans,   // [4][4]
    const float* __restrict__ strans,  // [4]
    const float* __restrict__ etrans,  // [4]
    const int*   __restrict__ mask,    // [32][512]
    int* __restrict__ out)             // [32][512]
{
  __shared__ float em_l[512 * 4];
  __shared__ int   msk_l[512];
  __shared__ int   hist_l[512 * 4];
  __shared__ int   tags_l[512];

  const int b = blockIdx.x;
  const int tid = threadIdx.x;
  const float* ep = em + (size_t)b * L_ * 4;

  for (int i = tid; i < 512; i += 64) {
    *(f32x4*)&em_l[i * 4] = *(const f32x4*)&ep[i * 4];
    msk_l[i] = mask[b * L_ + i];
  }
  __syncthreads();

  if (tid == 0) {
    float tr[4][4];
#pragma unroll
    for (int i = 0; i < 4; ++i)
#pragma unroll
      for (int jj = 0; jj < 4; ++jj) tr[i][jj] = trans[i * 4 + jj];

    float sc[4];
#pragma unroll
    for (int tag = 0; tag < 4; ++tag) sc[tag] = strans[tag] + em_l[tag];

    for (int t = 1; t < L_; ++t) {
      float ns[4];
#pragma unroll
      for (int to = 0; to < 4; ++to) {
        float best = sc[0] + tr[0][to];
        int bf = 0;
#pragma unroll
        for (int fr = 1; fr < 4; ++fr) {
          float v = sc[fr] + tr[fr][to];
          if (v > best) { best = v; bf = fr; }
        }
        ns[to] = best + em_l[t * 4 + to];
        hist_l[t * 4 + to] = bf;
      }
      const int mt = msk_l[t];
#pragma unroll
      for (int to = 0; to < 4; ++to) sc[to] = mt ? ns[to] : sc[to];
    }

#pragma unroll
    for (int tag = 0; tag < 4; ++tag) sc[tag] += etrans[tag];
    int cur = 0;
    float best = sc[0];
#pragma unroll
    for (int i = 1; i < 4; ++i)
      if (sc[i] > best) { best = sc[i]; cur = i; }

    tags_l[L_ - 1] = msk_l[L_ - 1] ? cur : 0;
    for (int t = L_ - 1; t >= 1; --t) {
      if (msk_l[t]) cur = hist_l[t * 4 + cur];
      tags_l[t - 1] = msk_l[t - 1] ? cur : 0;
    }
  }
  __syncthreads();
  for (int i = tid; i < 512; i += 64) out[b * L_ + i] = tags_l[i];
}

extern "C" void kernel_launch(void* const* d_in, const int* in_sizes, int n_in,
                              void* d_out, int out_size, void* d_ws, size_t ws_size,
                              hipStream_t stream) {
  const int*   word_ids = (const int*)d_in[0];
  const int*   mask     = (const int*)d_in[1];
  // d_in[2] label_ids: unused
  const float* emb   = (const float*)d_in[3];
  const float* Wih_f = (const float*)d_in[4];
  const float* Whh_f = (const float*)d_in[5];
  const float* b_f   = (const float*)d_in[6];
  const float* Wih_b = (const float*)d_in[7];
  const float* Whh_b = (const float*)d_in[8];
  const float* b_b   = (const float*)d_in[9];
  const float* W_out = (const float*)d_in[10];
  const float* b_out = (const float*)d_in[11];
  const float* trans = (const float*)d_in[12];
  const float* strans = (const float*)d_in[13];
  const float* etrans = (const float*)d_in[14];
  int* out = (int*)d_out;

  float* xg    = (float*)d_ws;                             // 128 MiB
  float* h_all = xg + (size_t)NTOK * XGLD;                 // 16*512*1024 f32 = 33.5 MB
  float* em    = h_all + (size_t)16 * L_ * 1024;           // 256 KiB

  const int n4 = 16 * L_ * 1024 / 4;                       // 2,097,152 f32x4
  fill_sentinel<<<(n4 + 255) / 256, 256, 0, stream>>>(h_all, n4);
  xproj_kernel<<<dim3(32, 256), 256, 0, stream>>>(word_ids, emb, Wih_f, Wih_b, b_f, b_b, xg);
  lstm_kernel<<<256, 512, 0, stream>>>(xg, Whh_f, Whh_b, h_all);
  emis_kernel<<<4096, 256, 0, stream>>>(h_all, W_out, b_out, em);
  viterbi_kernel<<<32, 64, 0, stream>>>(em, trans, strans, etrans, mask, out);
}

// Round 14
// 1086.525 us; speedup vs baseline: 1.1022x; 1.1022x over previous
//
#include <hip/hip_runtime.h>
#include <math.h>

#define B_   32
#define L_   512
#define E_   300
#define H_   256
#define T_   4
#define NTOK 16384  // B*L
#define XGLD 2048   // 2 directions * 4H
#define SENT 2.0f   // impossible h value: |h| = |sigm*tanh| < 1

typedef float f32x4 __attribute__((ext_vector_type(4)));
typedef float f32x2 __attribute__((ext_vector_type(2)));

__device__ __forceinline__ float fsigmoid_(float x) { return 1.0f / (1.0f + __expf(-x)); }
__device__ __forceinline__ float ftanh_(float x) {
  return 1.0f - 2.0f / (__expf(2.0f * x) + 1.0f);   // exact limits at +-inf
}

// LLC-coherent (agent-scope) vector ops: sc0 sc1 bypass L1/L2 like relaxed
// agent atomics, but vectorized. Caller must s_waitcnt vmcnt before using loads.
__device__ __forceinline__ void llc_store_f32(float* p, float v) {
  asm volatile("global_store_dword %0, %1, off sc0 sc1" :: "v"(p), "v"(v) : "memory");
}
__device__ __forceinline__ void llc_store_f32x4(float* p, f32x4 v) {
  asm volatile("global_store_dwordx4 %0, %1, off sc0 sc1" :: "v"(p), "v"(v) : "memory");
}
__device__ __forceinline__ f32x4 llc_load_f32x4(const float* p) {
  f32x4 r;
  asm volatile("global_load_dwordx4 %0, %1, off sc0 sc1" : "=&v"(r) : "v"(p) : "memory");
  return r;
}

// ---------- stage A: xg[row][d*1024+g] = emb[wid[row]] . Wih_d[g] + b_d[g] ----------
// 128x128 block, 8x8 per-thread tile: 4 ds_read_b128 per 64 FMAs.
#define XBM 128
#define XBN 128
#define XBK 20
__global__ __launch_bounds__(256) void xproj_kernel(
    const int*   __restrict__ wid,    // [NTOK]
    const float* __restrict__ emb,    // [V][300]
    const float* __restrict__ wih_f,  // [1024][300]
    const float* __restrict__ wih_b,
    const float* __restrict__ b_f,
    const float* __restrict__ b_b,
    float* __restrict__ xg)           // [NTOK][2048]
{
  __shared__ float Ast[XBK][XBM];    // [k][m]  10 KB
  __shared__ float Bst[XBK][XBN];    // [k][n]  10 KB
  __shared__ int   wid_s[XBM];

  const int tid = threadIdx.x;
  const int m0 = blockIdx.y * XBM;
  const int n0 = blockIdx.x * XBN;   // 0..2047 in steps of 128
  const int d  = n0 >> 10;
  const float* wih  = d ? wih_b : wih_f;
  const float* bias = d ? b_b  : b_f;
  const int g0 = n0 & 1023;

  if (tid < XBM) wid_s[tid] = wid[m0 + tid];
  __syncthreads();

  const int tx = tid & 15, ty = tid >> 4;
  float acc[8][8] = {};

  for (int k0 = 0; k0 < 300; k0 += XBK) {
    // ---- stage A (gathered emb rows), transposed: 128 rows x 5 quads ----
    for (int idx = tid; idx < 640; idx += 256) {
      const int row = idx / 5, quad = idx - row * 5;
      f32x4 v = *(const f32x4*)(emb + (size_t)wid_s[row] * E_ + k0 + quad * 4);
      Ast[quad * 4 + 0][row] = v.x;
      Ast[quad * 4 + 1][row] = v.y;
      Ast[quad * 4 + 2][row] = v.z;
      Ast[quad * 4 + 3][row] = v.w;
    }
    // ---- stage B (weight rows), transposed ----
    for (int idx = tid; idx < 640; idx += 256) {
      const int row = idx / 5, quad = idx - row * 5;
      f32x4 v = *(const f32x4*)(wih + (size_t)(g0 + row) * E_ + k0 + quad * 4);
      Bst[quad * 4 + 0][row] = v.x;
      Bst[quad * 4 + 1][row] = v.y;
      Bst[quad * 4 + 2][row] = v.z;
      Bst[quad * 4 + 3][row] = v.w;
    }
    __syncthreads();

#pragma unroll
    for (int k = 0; k < XBK; ++k) {
      float av[8], bv[8];
      *(f32x4*)&av[0] = *(const f32x4*)&Ast[k][ty * 8];
      *(f32x4*)&av[4] = *(const f32x4*)&Ast[k][ty * 8 + 4];
      *(f32x4*)&bv[0] = *(const f32x4*)&Bst[k][tx * 8];
      *(f32x4*)&bv[4] = *(const f32x4*)&Bst[k][tx * 8 + 4];
#pragma unroll
      for (int i = 0; i < 8; ++i)
#pragma unroll
        for (int j = 0; j < 8; ++j)
          acc[i][j] += av[i] * bv[j];
    }
    __syncthreads();
  }

#pragma unroll
  for (int i = 0; i < 8; ++i) {
    const int r = m0 + ty * 8 + i;
    float* op = xg + (size_t)r * XGLD + n0 + tx * 8;
#pragma unroll
    for (int j = 0; j < 8; ++j)
      op[j] = acc[i][j] + bias[g0 + tx * 8 + j];
  }
}

// ---------- sentinel fill for h_all (replay-safe, runs every launch) ----------
__global__ __launch_bounds__(256) void fill_sentinel(float* p, int n4) {
  int i = blockIdx.x * 256 + threadIdx.x;
  if (i < n4) {
    f32x4 v = {SENT, SENT, SENT, SENT};
    llc_store_f32x4(p + (size_t)i * 4, v);
  }
}

// ---------- stage B: LSTM, 256 blocks, 2-phase batch pipeline (round-12 proven) -----
// Block = (d, q eighth of 4 batches, sl slice of 16 units = 64 gate rows, unit-major).
// Phases: A = batches {0,1}, B = {2,3}. 4-slot schedule per step:
//   slot1 GEMM_A(s) | slot2 reduce_A(s)+pub || spin_B(s-1) | slot3 GEMM_B(s) |
//   slot4 reduce_B(s)+pub || spin_A(s)
__global__ __launch_bounds__(512, 2) void lstm_kernel(
    const float* __restrict__ xg,     // [NTOK][2048]
    const float* __restrict__ whh_f,  // [1024][256]
    const float* __restrict__ whh_b,  // [1024][256]
    float*       h_all)               // [16 grp][512 t][4 bl][256 j]
{
  const int bid = blockIdx.x;        // 0..255
  const int d   = bid >> 7;
  const int q   = (bid >> 4) & 7;    // batch eighth
  const int sl  = bid & 15;          // slice
  const int tid = threadIdx.x;
  const int kp  = tid >> 6;          // 0..7 (wave / k-chunk)
  const int lane = tid & 63;
  const int bl_loc = lane >> 5;      // batch within phase (0/1)
  const int rg  = lane & 31;         // row pair index
  const float* __restrict__ whh = d ? whh_b : whh_f;

  __shared__ float h_lds[4 * 260];           // h[bl][k+pad]             (4.2 KB)
  __shared__ float part_lds[2 * 8 * 2 * 72]; // [ph][kp][bl_loc][row+pad] (9.2 KB)

  // ---- per-thread weights: rows rg*2, rg*2+1 (unit-major), k-chunk kp ----
  f32x4 wreg[2][8];
#pragma unroll
  for (int r = 0; r < 2; ++r) {
    const int row_l = rg * 2 + r;            // u*4 + gt
    const int u  = row_l >> 2;
    const int gt = row_l & 3;
    const int grow = gt * 256 + sl * 16 + u;
    const float* rp = whh + (size_t)grow * H_ + kp * 32;
#pragma unroll
    for (int qq = 0; qq < 8; ++qq) wreg[r][qq] = *(const f32x4*)(rp + qq * 4);
  }

  for (int idx = tid; idx < 4 * 260; idx += 512) h_lds[idx] = 0.f;
  __syncthreads();

  float* hgrp = h_all + (size_t)(d * 8 + q) * (L_ * 1024);   // [512 t][4 bl][256 j]

  // reduce-thread state: tid<32 -> phase A (bl 0,1); tid 32..63 -> phase B (bl 2,3)
  const int r_u  = (tid & 31) >> 1;
  const int r_bl = (tid < 32) ? (tid & 1) : (2 + (tid & 1));
  float c = 0.f;
  const float* xbase = xg + ((size_t)(q * 4 + r_bl) * L_) * XGLD + d * 1024 + sl * 16 + r_u;
  float x0 = 0.f, x1 = 0.f, x2 = 0.f, x3 = 0.f;
  if (tid < 64) {
    const int t0 = d ? (L_ - 1) : 0;
    const float* xp = xbase + (size_t)t0 * XGLD;
    x0 = xp[0]; x1 = xp[256]; x2 = xp[512]; x3 = xp[768];
  }

#define GEMM_PHASE(PH, BLBASE)                                                \
  do {                                                                        \
    const int blg = (BLBASE) + bl_loc;                                        \
    const float* hb = &h_lds[blg * 260 + kp * 32];                            \
    float a0 = 0.f, a1 = 0.f;                                                 \
    _Pragma("unroll")                                                         \
    for (int i = 0; i < 8; ++i) {                                             \
      f32x4 hv = *(const f32x4*)(hb + i * 4);                                 \
      a0 += wreg[0][i].x * hv.x + wreg[0][i].y * hv.y                         \
          + wreg[0][i].z * hv.z + wreg[0][i].w * hv.w;                        \
      a1 += wreg[1][i].x * hv.x + wreg[1][i].y * hv.y                         \
          + wreg[1][i].z * hv.z + wreg[1][i].w * hv.w;                        \
    }                                                                         \
    f32x2 pv = {a0, a1};                                                      \
    *(f32x2*)&part_lds[(PH) * 1152 + kp * 144 + bl_loc * 72 + rg * 2] = pv;   \
  } while (0)

#define REDUCE_PUBLISH(PH, TT, TN)                                            \
  do {                                                                        \
    f32x4 g = {x0, x1, x2, x3};                                               \
    _Pragma("unroll")                                                         \
    for (int k2 = 0; k2 < 8; ++k2)                                            \
      g += *(const f32x4*)&part_lds[(PH) * 1152 + k2 * 144                    \
                                    + (tid & 1) * 72 + r_u * 4];              \
    float gi = fsigmoid_(g.x);                                                \
    float gf = fsigmoid_(g.y);                                                \
    float gg = ftanh_(g.z);                                                   \
    float go = fsigmoid_(g.w);                                                \
    c = gf * c + gi * gg;                                                     \
    float h = go * ftanh_(c);                                                 \
    llc_store_f32(&hgrp[(size_t)(TT) * 1024 + r_bl * 256 + sl * 16 + r_u], h);\
    if ((TN) >= 0) {                                                          \
      const float* xp = xbase + (size_t)(TN) * XGLD;                          \
      x0 = xp[0]; x1 = xp[256]; x2 = xp[512]; x3 = xp[768];                   \
    }                                                                         \
  } while (0)

#define SPIN_LOAD(BLBASE, TT)                                                 \
  do {                                                                        \
    const int i = tid - 64;                                                   \
    const int blg = (BLBASE) + (i >> 6);                                      \
    const int j4 = (i & 63) * 4;                                              \
    const float* p0 = hgrp + (size_t)(TT) * 1024 + blg * 256 + j4;            \
    f32x4 v0;                                                                 \
    bool bad;                                                                 \
    do {                                                                      \
      v0 = llc_load_f32x4(p0);                                                \
      asm volatile("s_waitcnt vmcnt(0)" ::: "memory");                        \
      __builtin_amdgcn_sched_barrier(0);                                      \
      bad = (v0.x == SENT) | (v0.y == SENT) | (v0.z == SENT) | (v0.w == SENT);\
    } while (bad);                                                            \
    *(f32x4*)&h_lds[blg * 260 + j4] = v0;                                     \
  } while (0)

  for (int s = 0; s < L_; ++s) {
    const int t  = d ? (L_ - 1 - s) : s;
    const int tp = d ? (t + 1) : (t - 1);          // previous step's time index
    const int tn = (s < L_ - 1) ? (d ? (t - 1) : (t + 1)) : -1;

    // ---- slot1: GEMM phase A ----
    GEMM_PHASE(0, 0);
    __syncthreads();

    // ---- slot2: reduce/publish A(s)  ||  spin B(s-1) ----
    if (tid < 32) {
      REDUCE_PUBLISH(0, t, tn);
    } else if (s > 0 && tid >= 64 && tid < 192) {
      SPIN_LOAD(2, tp);
    }
    __syncthreads();

    // ---- slot3: GEMM phase B ----
    GEMM_PHASE(1, 2);
    __syncthreads();

    // ---- slot4: reduce/publish B(s)  ||  spin A(s) ----
    if (tid >= 32 && tid < 64) {
      REDUCE_PUBLISH(1, t, tn);
    } else if (s < L_ - 1 && tid >= 64 && tid < 192) {
      SPIN_LOAD(0, t);
    }
    __syncthreads();
  }

#undef GEMM_PHASE
#undef REDUCE_PUBLISH
#undef SPIN_LOAD
}

// ---------- emissions: block = (t, q); em[b][t][tag] = bout + h_f.Wf + h_b.Wb ------
__global__ __launch_bounds__(256) void emis_kernel(
    const float* __restrict__ h_all,  // [16][512][4][256]
    const float* __restrict__ wout,   // [4][512]
    const float* __restrict__ bout,   // [4]
    float* __restrict__ em)           // [32][512][4]
{
  __shared__ float hf_l[1024];   // [bl][j]
  __shared__ float hb_l[1024];
  __shared__ float wsl[2048];

  const int t  = blockIdx.x >> 3;
  const int q  = blockIdx.x & 7;
  const int tid = threadIdx.x;
  const float* hfp = h_all + ((size_t)(0 + q) * L_ + t) * 1024;
  const float* hbp = h_all + ((size_t)(8 + q) * L_ + t) * 1024;

  if (tid < 256) {
    *(f32x4*)&hf_l[tid * 4] = *(const f32x4*)&hfp[tid * 4];
    *(f32x4*)&hb_l[tid * 4] = *(const f32x4*)&hbp[tid * 4];
  }
  for (int i = tid; i < 2048; i += 256) wsl[i] = wout[i];
  __syncthreads();

  const int bl = tid >> 6, lane = tid & 63;
  float s0 = 0.f, s1 = 0.f, s2 = 0.f, s3 = 0.f;
#pragma unroll
  for (int i = 0; i < 4; ++i) {
    const int j = i * 64 + lane;
    const float hfv = hf_l[bl * 256 + j], hbv = hb_l[bl * 256 + j];
    s0 += hfv * wsl[0 * 512 + j] + hbv * wsl[0 * 512 + 256 + j];
    s1 += hfv * wsl[1 * 512 + j] + hbv * wsl[1 * 512 + 256 + j];
    s2 += hfv * wsl[2 * 512 + j] + hbv * wsl[2 * 512 + 256 + j];
    s3 += hfv * wsl[3 * 512 + j] + hbv * wsl[3 * 512 + 256 + j];
  }
#pragma unroll
  for (int m = 1; m < 64; m <<= 1) {
    s0 += __shfl_xor(s0, m, 64);
    s1 += __shfl_xor(s1, m, 64);
    s2 += __shfl_xor(s2, m, 64);
    s3 += __shfl_xor(s3, m, 64);
  }
  if (lane == 0) {
    float* ep = em + ((size_t)(q * 4 + bl) * L_ + t) * 4;
    ep[0] = s0 + bout[0]; ep[1] = s1 + bout[1];
    ep[2] = s2 + bout[2]; ep[3] = s3 + bout[3];
  }
}

// ---------- Viterbi decode: one block per batch, em/hist staged in LDS ----------
__global__ __launch_bounds__(64) void viterbi_kernel(
    const float* __restrict__ em,      // [32][512][4]  (bias included)
    const float* __restrict__ trans,   // [4][4]
    const float* __restrict__ strans,  // [4]
    const float* __restrict__ etrans,  // [4]
    const int*   __restrict__ mask,    // [32][512]
    int* __restrict__ out)             // [32][512]
{
  __shared__ float em_l[512 * 4];
  __shared__ int   msk_l[512];
  __shared__ int   hist_l[512 * 4];
  __shared__ int   tags_l[512];

  const int b = blockIdx.x;
  const int tid = threadIdx.x;
  const float* ep = em + (size_t)b * L_ * 4;

  for (int i = tid; i < 512; i += 64) {
    *(f32x4*)&em_l[i * 4] = *(const f32x4*)&ep[i * 4];
    msk_l[i] = mask[b * L_ + i];
  }
  __syncthreads();

  if (tid == 0) {
    float tr[4][4];
#pragma unroll
    for (int i = 0; i < 4; ++i)
#pragma unroll
      for (int jj = 0; jj < 4; ++jj) tr[i][jj] = trans[i * 4 + jj];

    float sc[4];
#pragma unroll
    for (int tag = 0; tag < 4; ++tag) sc[tag] = strans[tag] + em_l[tag];

    for (int t = 1; t < L_; ++t) {
      float ns[4];
#pragma unroll
      for (int to = 0; to < 4; ++to) {
        float best = sc[0] + tr[0][to];
        int bf = 0;
#pragma unroll
        for (int fr = 1; fr < 4; ++fr) {
          float v = sc[fr] + tr[fr][to];
          if (v > best) { best = v; bf = fr; }
        }
        ns[to] = best + em_l[t * 4 + to];
        hist_l[t * 4 + to] = bf;
      }
      const int mt = msk_l[t];
#pragma unroll
      for (int to = 0; to < 4; ++to) sc[to] = mt ? ns[to] : sc[to];
    }

#pragma unroll
    for (int tag = 0; tag < 4; ++tag) sc[tag] += etrans[tag];
    int cur = 0;
    float best = sc[0];
#pragma unroll
    for (int i = 1; i < 4; ++i)
      if (sc[i] > best) { best = sc[i]; cur = i; }

    tags_l[L_ - 1] = msk_l[L_ - 1] ? cur : 0;
    for (int t = L_ - 1; t >= 1; --t) {
      if (msk_l[t]) cur = hist_l[t * 4 + cur];
      tags_l[t - 1] = msk_l[t - 1] ? cur : 0;
    }
  }
  __syncthreads();
  for (int i = tid; i < 512; i += 64) out[b * L_ + i] = tags_l[i];
}

extern "C" void kernel_launch(void* const* d_in, const int* in_sizes, int n_in,
                              void* d_out, int out_size, void* d_ws, size_t ws_size,
                              hipStream_t stream) {
  const int*   word_ids = (const int*)d_in[0];
  const int*   mask     = (const int*)d_in[1];
  // d_in[2] label_ids: unused
  const float* emb   = (const float*)d_in[3];
  const float* Wih_f = (const float*)d_in[4];
  const float* Whh_f = (const float*)d_in[5];
  const float* b_f   = (const float*)d_in[6];
  const float* Wih_b = (const float*)d_in[7];
  const float* Whh_b = (const float*)d_in[8];
  const float* b_b   = (const float*)d_in[9];
  const float* W_out = (const float*)d_in[10];
  const float* b_out = (const float*)d_in[11];
  const float* trans = (const float*)d_in[12];
  const float* strans = (const float*)d_in[13];
  const float* etrans = (const float*)d_in[14];
  int* out = (int*)d_out;

  float* xg    = (float*)d_ws;                             // 128 MiB
  float* h_all = xg + (size_t)NTOK * XGLD;                 // 16*512*1024 f32 = 33.5 MB
  float* em    = h_all + (size_t)16 * L_ * 1024;           // 256 KiB

  const int n4 = 16 * L_ * 1024 / 4;                       // 2,097,152 f32x4
  fill_sentinel<<<(n4 + 255) / 256, 256, 0, stream>>>(h_all, n4);
  xproj_kernel<<<dim3(16, 128), 256, 0, stream>>>(word_ids, emb, Wih_f, Wih_b, b_f, b_b, xg);
  lstm_kernel<<<256, 512, 0, stream>>>(xg, Whh_f, Whh_b, h_all);
  emis_kernel<<<4096, 256, 0, stream>>>(h_all, W_out, b_out, em);
  viterbi_kernel<<<32, 64, 0, stream>>>(em, trans, strans, etrans, mask, out);
}

// Round 15
// 1048.627 us; speedup vs baseline: 1.1420x; 1.0361x over previous
//
#include <hip/hip_runtime.h>
#include <math.h>

#define B_   32
#define L_   512
#define E_   300
#define H_   256
#define T_   4
#define NTOK 16384  // B*L
#define XGLD 2048   // 2 directions * 4H
#define SENT 2.0f   // impossible h value: |h| = |sigm*tanh| < 1

typedef float f32x4 __attribute__((ext_vector_type(4)));
typedef float f32x2 __attribute__((ext_vector_type(2)));

__device__ __forceinline__ float fsigmoid_(float x) { return 1.0f / (1.0f + __expf(-x)); }
__device__ __forceinline__ float ftanh_(float x) {
  return 1.0f - 2.0f / (__expf(2.0f * x) + 1.0f);   // exact limits at +-inf
}

// LLC-coherent (agent-scope) vector ops: sc0 sc1 bypass L1/L2 like relaxed
// agent atomics, but vectorized. Caller must s_waitcnt vmcnt before using loads.
__device__ __forceinline__ void llc_store_f32(float* p, float v) {
  asm volatile("global_store_dword %0, %1, off sc0 sc1" :: "v"(p), "v"(v) : "memory");
}
__device__ __forceinline__ void llc_store_f32x4(float* p, f32x4 v) {
  asm volatile("global_store_dwordx4 %0, %1, off sc0 sc1" :: "v"(p), "v"(v) : "memory");
}
__device__ __forceinline__ f32x4 llc_load_f32x4(const float* p) {
  f32x4 r;
  asm volatile("global_load_dwordx4 %0, %1, off sc0 sc1" : "=&v"(r) : "v"(p) : "memory");
  return r;
}

// ---------- stage A: xg[row][d*1024+g] = emb[wid[row]] . Wih_d[g] + b_d[g] ----------
// 128x128 block, 8x8 per-thread tile, register-prefetch software pipeline:
// waves 0-1 stage A (emb gather), waves 2-3 stage B; each thread holds its row's
// 5 f32x4 in regs; next tile's loads issue BEFORE compute so L3/HBM latency hides.
// Epilogue: grid-stride sentinel fill of h_all (folds the fill dispatch away).
#define XBM 128
#define XBN 128
#define XBK 20
__global__ __launch_bounds__(256) void xproj_kernel(
    const int*   __restrict__ wid,    // [NTOK]
    const float* __restrict__ emb,    // [V][300]
    const float* __restrict__ wih_f,  // [1024][300]
    const float* __restrict__ wih_b,
    const float* __restrict__ b_f,
    const float* __restrict__ b_b,
    float* __restrict__ xg,           // [NTOK][2048]
    float*       h_all,               // sentinel-fill target
    int          n4)                  // h_all size in f32x4
{
  __shared__ float Ast[XBK][XBM];    // [k][m]  10 KB
  __shared__ float Bst[XBK][XBN];    // [k][n]  10 KB
  __shared__ int   wid_s[XBM];

  const int tid = threadIdx.x;
  const int m0 = blockIdx.y * XBM;
  const int n0 = blockIdx.x * XBN;   // 0..2047 in steps of 128
  const int d  = n0 >> 10;
  const float* wih  = d ? wih_b : wih_f;
  const float* bias = d ? b_b  : b_f;
  const int g0 = n0 & 1023;

  if (tid < XBM) wid_s[tid] = wid[m0 + tid];
  __syncthreads();

  // staging role: waves 0-1 -> A (emb rows via gather), waves 2-3 -> B (wih rows)
  const int srow = tid & 127;
  const int half = tid >> 7;         // wave-uniform
  const float* sbase = half ? (wih + (size_t)(g0 + srow) * E_)
                            : (emb + (size_t)wid_s[srow] * E_);
  float* sdst = half ? &Bst[0][0] : &Ast[0][0];

  f32x4 pre[5];
#pragma unroll
  for (int qd = 0; qd < 5; ++qd) pre[qd] = *(const f32x4*)(sbase + qd * 4);

  const int tx = tid & 15, ty = tid >> 4;
  float acc[8][8] = {};

  for (int k0 = 0; k0 < 300; k0 += XBK) {
    // store prefetched tile -> LDS transposed (stride-1 across lanes: conflict-free)
#pragma unroll
    for (int qd = 0; qd < 5; ++qd)
#pragma unroll
      for (int e = 0; e < 4; ++e)
        sdst[(qd * 4 + e) * XBM + srow] = pre[qd][e];
    // issue next tile's global loads now; latency hides under compute below
    if (k0 + XBK < 300) {
      const float* p = sbase + k0 + XBK;
#pragma unroll
      for (int qd = 0; qd < 5; ++qd) pre[qd] = *(const f32x4*)(p + qd * 4);
    }
    __syncthreads();

#pragma unroll
    for (int k = 0; k < XBK; ++k) {
      float av[8], bv[8];
      *(f32x4*)&av[0] = *(const f32x4*)&Ast[k][ty * 8];
      *(f32x4*)&av[4] = *(const f32x4*)&Ast[k][ty * 8 + 4];
      *(f32x4*)&bv[0] = *(const f32x4*)&Bst[k][tx * 8];
      *(f32x4*)&bv[4] = *(const f32x4*)&Bst[k][tx * 8 + 4];
#pragma unroll
      for (int i = 0; i < 8; ++i)
#pragma unroll
        for (int j = 0; j < 8; ++j)
          acc[i][j] += av[i] * bv[j];
    }
    __syncthreads();
  }

#pragma unroll
  for (int i = 0; i < 8; ++i) {
    const int r = m0 + ty * 8 + i;
    float* op = xg + (size_t)r * XGLD + n0 + tx * 8;
#pragma unroll
    for (int j = 0; j < 8; ++j)
      op[j] = acc[i][j] + bias[g0 + tx * 8 + j];
  }

  // ---- sentinel fill epilogue (replay-safe; complete before lstm by stream order) --
  {
    const int blin = blockIdx.y * 16 + blockIdx.x;   // 0..2047
    f32x4 sv = {SENT, SENT, SENT, SENT};
    for (int i = blin * 256 + tid; i < n4; i += 2048 * 256)
      llc_store_f32x4(h_all + (size_t)i * 4, sv);
  }
}

// ---------- stage B: LSTM, 256 blocks, 2-phase batch pipeline (round-12 proven) -----
// Block = (d, q eighth of 4 batches, sl slice of 16 units = 64 gate rows, unit-major).
// Phases: A = batches {0,1}, B = {2,3}. 4-slot schedule per step:
//   slot1 GEMM_A(s) | slot2 reduce_A(s)+pub || spin_B(s-1) | slot3 GEMM_B(s) |
//   slot4 reduce_B(s)+pub || spin_A(s)
__global__ __launch_bounds__(512, 2) void lstm_kernel(
    const float* __restrict__ xg,     // [NTOK][2048]
    const float* __restrict__ whh_f,  // [1024][256]
    const float* __restrict__ whh_b,  // [1024][256]
    float*       h_all)               // [16 grp][512 t][4 bl][256 j]
{
  const int bid = blockIdx.x;        // 0..255
  const int d   = bid >> 7;
  const int q   = (bid >> 4) & 7;    // batch eighth
  const int sl  = bid & 15;          // slice
  const int tid = threadIdx.x;
  const int kp  = tid >> 6;          // 0..7 (wave / k-chunk)
  const int lane = tid & 63;
  const int bl_loc = lane >> 5;      // batch within phase (0/1)
  const int rg  = lane & 31;         // row pair index
  const float* __restrict__ whh = d ? whh_b : whh_f;

  __shared__ float h_lds[4 * 260];           // h[bl][k+pad]             (4.2 KB)
  __shared__ float part_lds[2 * 8 * 2 * 72]; // [ph][kp][bl_loc][row+pad] (9.2 KB)

  // ---- per-thread weights: rows rg*2, rg*2+1 (unit-major), k-chunk kp ----
  f32x4 wreg[2][8];
#pragma unroll
  for (int r = 0; r < 2; ++r) {
    const int row_l = rg * 2 + r;            // u*4 + gt
    const int u  = row_l >> 2;
    const int gt = row_l & 3;
    const int grow = gt * 256 + sl * 16 + u;
    const float* rp = whh + (size_t)grow * H_ + kp * 32;
#pragma unroll
    for (int qq = 0; qq < 8; ++qq) wreg[r][qq] = *(const f32x4*)(rp + qq * 4);
  }

  for (int idx = tid; idx < 4 * 260; idx += 512) h_lds[idx] = 0.f;
  __syncthreads();

  float* hgrp = h_all + (size_t)(d * 8 + q) * (L_ * 1024);   // [512 t][4 bl][256 j]

  // reduce-thread state: tid<32 -> phase A (bl 0,1); tid 32..63 -> phase B (bl 2,3)
  const int r_u  = (tid & 31) >> 1;
  const int r_bl = (tid < 32) ? (tid & 1) : (2 + (tid & 1));
  float c = 0.f;
  const float* xbase = xg + ((size_t)(q * 4 + r_bl) * L_) * XGLD + d * 1024 + sl * 16 + r_u;
  float x0 = 0.f, x1 = 0.f, x2 = 0.f, x3 = 0.f;
  if (tid < 64) {
    const int t0 = d ? (L_ - 1) : 0;
    const float* xp = xbase + (size_t)t0 * XGLD;
    x0 = xp[0]; x1 = xp[256]; x2 = xp[512]; x3 = xp[768];
  }

#define GEMM_PHASE(PH, BLBASE)                                                \
  do {                                                                        \
    const int blg = (BLBASE) + bl_loc;                                        \
    const float* hb = &h_lds[blg * 260 + kp * 32];                            \
    float a0 = 0.f, a1 = 0.f;                                                 \
    _Pragma("unroll")                                                         \
    for (int i = 0; i < 8; ++i) {                                             \
      f32x4 hv = *(const f32x4*)(hb + i * 4);                                 \
      a0 += wreg[0][i].x * hv.x + wreg[0][i].y * hv.y                         \
          + wreg[0][i].z * hv.z + wreg[0][i].w * hv.w;                        \
      a1 += wreg[1][i].x * hv.x + wreg[1][i].y * hv.y                         \
          + wreg[1][i].z * hv.z + wreg[1][i].w * hv.w;                        \
    }                                                                         \
    f32x2 pv = {a0, a1};                                                      \
    *(f32x2*)&part_lds[(PH) * 1152 + kp * 144 + bl_loc * 72 + rg * 2] = pv;   \
  } while (0)

#define REDUCE_PUBLISH(PH, TT, TN)                                            \
  do {                                                                        \
    f32x4 g = {x0, x1, x2, x3};                                               \
    _Pragma("unroll")                                                         \
    for (int k2 = 0; k2 < 8; ++k2)                                            \
      g += *(const f32x4*)&part_lds[(PH) * 1152 + k2 * 144                    \
                                    + (tid & 1) * 72 + r_u * 4];              \
    float gi = fsigmoid_(g.x);                                                \
    float gf = fsigmoid_(g.y);                                                \
    float gg = ftanh_(g.z);                                                   \
    float go = fsigmoid_(g.w);                                                \
    c = gf * c + gi * gg;                                                     \
    float h = go * ftanh_(c);                                                 \
    llc_store_f32(&hgrp[(size_t)(TT) * 1024 + r_bl * 256 + sl * 16 + r_u], h);\
    if ((TN) >= 0) {                                                          \
      const float* xp = xbase + (size_t)(TN) * XGLD;                          \
      x0 = xp[0]; x1 = xp[256]; x2 = xp[512]; x3 = xp[768];                   \
    }                                                                         \
  } while (0)

#define SPIN_LOAD(BLBASE, TT)                                                 \
  do {                                                                        \
    const int i = tid - 64;                                                   \
    const int blg = (BLBASE) + (i >> 6);                                      \
    const int j4 = (i & 63) * 4;                                              \
    const float* p0 = hgrp + (size_t)(TT) * 1024 + blg * 256 + j4;            \
    f32x4 v0;                                                                 \
    bool bad;                                                                 \
    do {                                                                      \
      v0 = llc_load_f32x4(p0);                                                \
      asm volatile("s_waitcnt vmcnt(0)" ::: "memory");                        \
      __builtin_amdgcn_sched_barrier(0);                                      \
      bad = (v0.x == SENT) | (v0.y == SENT) | (v0.z == SENT) | (v0.w == SENT);\
    } while (bad);                                                            \
    *(f32x4*)&h_lds[blg * 260 + j4] = v0;                                     \
  } while (0)

  for (int s = 0; s < L_; ++s) {
    const int t  = d ? (L_ - 1 - s) : s;
    const int tp = d ? (t + 1) : (t - 1);          // previous step's time index
    const int tn = (s < L_ - 1) ? (d ? (t - 1) : (t + 1)) : -1;

    // ---- slot1: GEMM phase A ----
    GEMM_PHASE(0, 0);
    __syncthreads();

    // ---- slot2: reduce/publish A(s)  ||  spin B(s-1) ----
    if (tid < 32) {
      REDUCE_PUBLISH(0, t, tn);
    } else if (s > 0 && tid >= 64 && tid < 192) {
      SPIN_LOAD(2, tp);
    }
    __syncthreads();

    // ---- slot3: GEMM phase B ----
    GEMM_PHASE(1, 2);
    __syncthreads();

    // ---- slot4: reduce/publish B(s)  ||  spin A(s) ----
    if (tid >= 32 && tid < 64) {
      REDUCE_PUBLISH(1, t, tn);
    } else if (s < L_ - 1 && tid >= 64 && tid < 192) {
      SPIN_LOAD(0, t);
    }
    __syncthreads();
  }

#undef GEMM_PHASE
#undef REDUCE_PUBLISH
#undef SPIN_LOAD
}

// ---------- emissions: block = (t, q); em[b][t][tag] = bout + h_f.Wf + h_b.Wb ------
__global__ __launch_bounds__(256) void emis_kernel(
    const float* __restrict__ h_all,  // [16][512][4][256]
    const float* __restrict__ wout,   // [4][512]
    const float* __restrict__ bout,   // [4]
    float* __restrict__ em)           // [32][512][4]
{
  __shared__ float hf_l[1024];   // [bl][j]
  __shared__ float hb_l[1024];
  __shared__ float wsl[2048];

  const int t  = blockIdx.x >> 3;
  const int q  = blockIdx.x & 7;
  const int tid = threadIdx.x;
  const float* hfp = h_all + ((size_t)(0 + q) * L_ + t) * 1024;
  const float* hbp = h_all + ((size_t)(8 + q) * L_ + t) * 1024;

  if (tid < 256) {
    *(f32x4*)&hf_l[tid * 4] = *(const f32x4*)&hfp[tid * 4];
    *(f32x4*)&hb_l[tid * 4] = *(const f32x4*)&hbp[tid * 4];
  }
  for (int i = tid; i < 2048; i += 256) wsl[i] = wout[i];
  __syncthreads();

  const int bl = tid >> 6, lane = tid & 63;
  float s0 = 0.f, s1 = 0.f, s2 = 0.f, s3 = 0.f;
#pragma unroll
  for (int i = 0; i < 4; ++i) {
    const int j = i * 64 + lane;
    const float hfv = hf_l[bl * 256 + j], hbv = hb_l[bl * 256 + j];
    s0 += hfv * wsl[0 * 512 + j] + hbv * wsl[0 * 512 + 256 + j];
    s1 += hfv * wsl[1 * 512 + j] + hbv * wsl[1 * 512 + 256 + j];
    s2 += hfv * wsl[2 * 512 + j] + hbv * wsl[2 * 512 + 256 + j];
    s3 += hfv * wsl[3 * 512 + j] + hbv * wsl[3 * 512 + 256 + j];
  }
#pragma unroll
  for (int m = 1; m < 64; m <<= 1) {
    s0 += __shfl_xor(s0, m, 64);
    s1 += __shfl_xor(s1, m, 64);
    s2 += __shfl_xor(s2, m, 64);
    s3 += __shfl_xor(s3, m, 64);
  }
  if (lane == 0) {
    float* ep = em + ((size_t)(q * 4 + bl) * L_ + t) * 4;
    ep[0] = s0 + bout[0]; ep[1] = s1 + bout[1];
    ep[2] = s2 + bout[2]; ep[3] = s3 + bout[3];
  }
}

// ---------- Viterbi decode: one block per batch, em/hist staged in LDS ----------
__global__ __launch_bounds__(64) void viterbi_kernel(
    const float* __restrict__ em,      // [32][512][4]  (bias included)
    const float* __restrict__ trans,   // [4][4]
    const float* __restrict__ strans,  // [4]
    const float* __restrict__ etrans,  // [4]
    const int*   __restrict__ mask,    // [32][512]
    int* __restrict__ out)             // [32][512]
{
  __shared__ float em_l[512 * 4];
  __shared__ int   msk_l[512];
  __shared__ int   hist_l[512 * 4];
  __shared__ int   tags_l[512];

  const int b = blockIdx.x;
  const int tid = threadIdx.x;
  const float* ep = em + (size_t)b * L_ * 4;

  for (int i = tid; i < 512; i += 64) {
    *(f32x4*)&em_l[i * 4] = *(const f32x4*)&ep[i * 4];
    msk_l[i] = mask[b * L_ + i];
  }
  __syncthreads();

  if (tid == 0) {
    float tr[4][4];
#pragma unroll
    for (int i = 0; i < 4; ++i)
#pragma unroll
      for (int jj = 0; jj < 4; ++jj) tr[i][jj] = trans[i * 4 + jj];

    float sc[4];
#pragma unroll
    for (int tag = 0; tag < 4; ++tag) sc[tag] = strans[tag] + em_l[tag];

    for (int t = 1; t < L_; ++t) {
      float ns[4];
#pragma unroll
      for (int to = 0; to < 4; ++to) {
        float best = sc[0] + tr[0][to];
        int bf = 0;
#pragma unroll
        for (int fr = 1; fr < 4; ++fr) {
          float v = sc[fr] + tr[fr][to];
          if (v > best) { best = v; bf = fr; }
        }
        ns[to] = best + em_l[t * 4 + to];
        hist_l[t * 4 + to] = bf;
      }
      const int mt = msk_l[t];
#pragma unroll
      for (int to = 0; to < 4; ++to) sc[to] = mt ? ns[to] : sc[to];
    }

#pragma unroll
    for (int tag = 0; tag < 4; ++tag) sc[tag] += etrans[tag];
    int cur = 0;
    float best = sc[0];
#pragma unroll
    for (int i = 1; i < 4; ++i)
      if (sc[i] > best) { best = sc[i]; cur = i; }

    tags_l[L_ - 1] = msk_l[L_ - 1] ? cur : 0;
    for (int t = L_ - 1; t >= 1; --t) {
      if (msk_l[t]) cur = hist_l[t * 4 + cur];
      tags_l[t - 1] = msk_l[t - 1] ? cur : 0;
    }
  }
  __syncthreads();
  for (int i = tid; i < 512; i += 64) out[b * L_ + i] = tags_l[i];
}

extern "C" void kernel_launch(void* const* d_in, const int* in_sizes, int n_in,
                              void* d_out, int out_size, void* d_ws, size_t ws_size,
                              hipStream_t stream) {
  const int*   word_ids = (const int*)d_in[0];
  const int*   mask     = (const int*)d_in[1];
  // d_in[2] label_ids: unused
  const float* emb   = (const float*)d_in[3];
  const float* Wih_f = (const float*)d_in[4];
  const float* Whh_f = (const float*)d_in[5];
  const float* b_f   = (const float*)d_in[6];
  const float* Wih_b = (const float*)d_in[7];
  const float* Whh_b = (const float*)d_in[8];
  const float* b_b   = (const float*)d_in[9];
  const float* W_out = (const float*)d_in[10];
  const float* b_out = (const float*)d_in[11];
  const float* trans = (const float*)d_in[12];
  const float* strans = (const float*)d_in[13];
  const float* etrans = (const float*)d_in[14];
  int* out = (int*)d_out;

  float* xg    = (float*)d_ws;                             // 128 MiB
  float* h_all = xg + (size_t)NTOK * XGLD;                 // 16*512*1024 f32 = 33.5 MB
  float* em    = h_all + (size_t)16 * L_ * 1024;           // 256 KiB

  const int n4 = 16 * L_ * 1024 / 4;                       // 2,097,152 f32x4
  xproj_kernel<<<dim3(16, 128), 256, 0, stream>>>(word_ids, emb, Wih_f, Wih_b,
                                                  b_f, b_b, xg, h_all, n4);
  lstm_kernel<<<256, 512, 0, stream>>>(xg, Whh_f, Whh_b, h_all);
  emis_kernel<<<4096, 256, 0, stream>>>(h_all, W_out, b_out, em);
  viterbi_kernel<<<32, 64, 0, stream>>>(em, trans, strans, etrans, mask, out);
}